// Round 4
// baseline (191.161 us; speedup 1.0000x reference)
//
#include <hip/hip_runtime.h>
#include <cstdint>
#include <cstddef>

#define D_MODEL 1024
#define D_STATE 64
#define SEQ     4096
#define BATCH   2
#define MROWS   (BATCH*SEQ)   // 8192 rows of activations

typedef __bf16 bf16x8 __attribute__((ext_vector_type(8)));
typedef float  f32x4  __attribute__((ext_vector_type(4)));
typedef unsigned short u16;
typedef unsigned int   u32;

union BF8 { bf16x8 v; uint4 q; u16 e[8]; };

__device__ __forceinline__ u16 f2bf(float x) {
    u32 u = __float_as_uint(x);
    u32 r = u + 0x7FFFu + ((u >> 16) & 1u);   // RNE on bf16 boundary
    return (u16)(r >> 16);
}
__device__ __forceinline__ float bf2f(u16 h) {
    return __uint_as_float(((u32)h) << 16);
}
__device__ __forceinline__ uint4 pack8u(const u16* e) {
    return make_uint4((u32)e[0] | ((u32)e[1] << 16), (u32)e[2] | ((u32)e[3] << 16),
                      (u32)e[4] | ((u32)e[5] << 16), (u32)e[6] | ((u32)e[7] << 16));
}

// async global->LDS, 16B per lane. LDS dest is wave-uniform base + lane*16.
__device__ __forceinline__ void async16(const void* g, void* l) {
    __builtin_amdgcn_global_load_lds(
        (const __attribute__((address_space(1))) unsigned int*)(uintptr_t)g,
        (__attribute__((address_space(3))) unsigned int*)(uintptr_t)l,
        16, 0, 0);
}

// ---------------------------------------------------------------------------
// prep: flat fp32 -> bf16 convert over [ x | Win | Wout ] -> [ Ax | Bw1 | Bw2 ].
// (unchanged — verified)
// ---------------------------------------------------------------------------
__global__ __launch_bounds__(256) void prep_kernel(
    const float* __restrict__ x, const float* __restrict__ Win,
    const float* __restrict__ Wout,
    u16* __restrict__ Ax, u16* __restrict__ Bw1, u16* __restrict__ Bw2)
{
    const size_t base = (size_t)blockIdx.x * 4096 + threadIdx.x * 4;
    const float* src; u16* dst; size_t off;
    if (base < 8388608)        { src = x;    dst = Ax;  off = base; }
    else if (base < 9437184)   { src = Win;  dst = Bw1; off = base - 8388608; }
    else                       { src = Wout; dst = Bw2; off = base - 9437184; }
    #pragma unroll
    for (int i = 0; i < 4; ++i) {
        const float4 v = *reinterpret_cast<const float4*>(src + off + i * 1024);
        *reinterpret_cast<uint2*>(dst + off + i * 1024) =
            make_uint2((u32)f2bf(v.x) | ((u32)f2bf(v.y) << 16),
                       (u32)f2bf(v.z) | ((u32)f2bf(v.w) << 16));
    }
}

// ---------------------------------------------------------------------------
// gemm_bt (v2): out[m,c] = sum_k A[m,k]*Bm[c,k] + bias[c], K=1024 bf16.
// 8-phase T-stack port (T2+T3+T4+T5):
//   BM=128 x BN=256 tile, 8 waves (2M x 4N -> 64x64 per wave), BK=64.
//   Grid = (8192/128)*(1024/256) = 256 blocks = exactly 1/CU @ 512 thr.
//   LDS: 3 full K-step buffers (A 16KB + B 32KB each) = 144 KiB -> 1 block/CU.
//   Pipeline depth 2: during step t we stage step t+2; per-step wait is a
//   COUNTED s_waitcnt vmcnt(6) (6 staging loads/thread/step in flight),
//   never a drain-to-0 in the main loop (T4). Per K-step: 4 phases, each
//   {8x ds_read_b128 | 2x global_load_lds | s_barrier | lgkmcnt(0) |
//    setprio(1) 8x MFMA setprio(0) | s_barrier}.
//   T2 swizzle: 16B-chunk index XOR (row&7), applied on the global SOURCE
//   address (linear global_load_lds dest) and on the ds_read address
//   (both-sides-or-neither, rule #21). Read banks: 8 lanes/16B-slot = wave64
//   minimum -> conflict-free.
//   XCD swizzle: bid&7 = XCD; each XCD owns 8 m-strips x all 4 n-blocks
//   (2MB A-panel + 2MB B = 4MB L2 working set), n fastest within XCD.
// Accumulation order (16 steps x kk=0,1) identical to previous verified
// kernel -> bit-identical results.
// MODE 0: fp32 [m][1024] store. MODE 1: transposed store into ut[b][c][l]
// via per-wave LDS patch (aliases dead GEMM LDS after final barrier).
// ---------------------------------------------------------------------------
#define PHASE(QI, QJ, STG)                                                    \
    {                                                                         \
        bf16x8 af[2][2], bg[2][2];                                            \
        _Pragma("unroll") for (int f = 0; f < 2; ++f) {                       \
            const int ar = wm * 64 + QI * 32 + f * 16 + qm;                   \
            const int br = wn * 64 + QJ * 32 + f * 16 + qm;                   \
            _Pragma("unroll") for (int kk = 0; kk < 2; ++kk) {                \
                const int ca = kk * 4 + qk;                                   \
                af[f][kk] = *reinterpret_cast<const bf16x8*>(                 \
                    &Ab[ar * 64 + ((ca ^ (ar & 7)) << 3)]);                   \
                bg[f][kk] = *reinterpret_cast<const bf16x8*>(                 \
                    &Bb[br * 64 + ((ca ^ (br & 7)) << 3)]);                   \
            }                                                                 \
        }                                                                     \
        STG;                                                                  \
        __builtin_amdgcn_s_barrier();                                         \
        asm volatile("s_waitcnt lgkmcnt(0)" ::: "memory");                    \
        __builtin_amdgcn_s_setprio(1);                                        \
        _Pragma("unroll") for (int kk = 0; kk < 2; ++kk)                      \
        _Pragma("unroll") for (int f = 0; f < 2; ++f)                         \
        _Pragma("unroll") for (int g = 0; g < 2; ++g)                         \
            acc[QI*2+f][QJ*2+g] = __builtin_amdgcn_mfma_f32_16x16x32_bf16(    \
                af[f][kk], bg[g][kk], acc[QI*2+f][QJ*2+g], 0, 0, 0);          \
        __builtin_amdgcn_s_setprio(0);                                        \
    }

template<int MODE>
__global__ __launch_bounds__(512, 2) void gemm_bt(
    const u16* __restrict__ A, const u16* __restrict__ Bm,
    const float* __restrict__ bias, float* __restrict__ out)
{
    // [0, 24576): 3 x A-buf (128x64 u16).  [24576, 73728): 3 x B-buf (256x64).
    __shared__ __align__(16) u16 L[73728];
    const int bid = blockIdx.x;
    const int id  = (bid & 7) * 32 + (bid >> 3);      // XCD-grouped tile id
    const int m0  = (id >> 2) * 128;
    const int n0  = (id & 3) * 256;
    const int tid  = threadIdx.x;
    const int wave = tid >> 6, lane = tid & 63;
    const int wm = wave >> 2, wn = wave & 3;          // 2M x 4N wave grid
    const int qm = lane & 15, qk = lane >> 4;
    f32x4 acc[4][4] = {};

    u16* const Abuf = L;            // 3 x 8192  u16
    u16* const Bbuf = L + 24576;    // 3 x 16384 u16

    // stage one 512-chunk slab (16B/thread). Linear LDS dest; source column
    // chunk pre-swizzled by (row&7) so swizzled data lands at linear dest.
    auto stageA = [&](int b, int k0, int it) {
        const int chunk = it * 512 + wave * 64 + lane;
        const int row = chunk >> 3, c16 = chunk & 7;
        async16(&A[(size_t)(m0 + row) * D_MODEL + k0 + ((c16 ^ (row & 7)) << 3)],
                Abuf + b * 8192 + (it * 512 + wave * 64) * 8);
    };
    auto stageB = [&](int b, int k0, int it) {
        const int chunk = it * 512 + wave * 64 + lane;
        const int row = chunk >> 3, c16 = chunk & 7;
        async16(&Bm[(size_t)(n0 + row) * D_MODEL + k0 + ((c16 ^ (row & 7)) << 3)],
                Bbuf + b * 16384 + (it * 512 + wave * 64) * 8);
    };

    // prologue: stage steps 0 and 1 (6 loads/thread each)
    #pragma unroll
    for (int it = 0; it < 2; ++it) stageA(0, 0, it);
    #pragma unroll
    for (int it = 0; it < 4; ++it) stageB(0, 0, it);
    #pragma unroll
    for (int it = 0; it < 2; ++it) stageA(1, 64, it);
    #pragma unroll
    for (int it = 0; it < 4; ++it) stageB(1, 64, it);
    asm volatile("s_waitcnt vmcnt(6)" ::: "memory");   // step-0 loads done
    __builtin_amdgcn_s_barrier();

    int cur = 0;
    #pragma unroll 1
    for (int t = 0; t < 16; ++t) {
        const u16* Ab = Abuf + cur * 8192;
        const u16* Bb = Bbuf + cur * 16384;
        const int nxt = (cur == 0) ? 2 : cur - 1;      // (t+2) % 3
        const int ks  = (t + 2) * 64;
        const bool st = t < 14;
        PHASE(0, 0, if (st) { stageA(nxt, ks, 0); stageA(nxt, ks, 1); })
        __builtin_amdgcn_s_barrier();
        PHASE(0, 1, if (st) { stageB(nxt, ks, 0); stageB(nxt, ks, 1); })
        __builtin_amdgcn_s_barrier();
        PHASE(1, 0, if (st) { stageB(nxt, ks, 2); stageB(nxt, ks, 3); })
        __builtin_amdgcn_s_barrier();
        PHASE(1, 1, ;)
        if (t < 14)       asm volatile("s_waitcnt vmcnt(6)" ::: "memory");
        else if (t == 14) asm volatile("s_waitcnt vmcnt(0)" ::: "memory");
        __builtin_amdgcn_s_barrier();
        cur = (cur == 2) ? 0 : cur + 1;
    }
    __syncthreads();   // all LDS reads done before MODE1 aliases the buffers

    // C/D layout: col = lane&15, row = (lane>>4)*4 + reg  [m89/m91-verified]
    if (MODE == 0) {
        #pragma unroll
        for (int i = 0; i < 4; ++i) {
            const int r0 = m0 + wm*64 + i*16 + qk*4;
            #pragma unroll
            for (int j = 0; j < 4; ++j) {
                const int c = n0 + wn*64 + j*16 + qm;
                const float bv = bias[c];
                #pragma unroll
                for (int reg = 0; reg < 4; ++reg)
                    out[(size_t)(r0 + reg) * D_MODEL + c] = acc[i][j][reg] + bv;
            }
        }
    } else {
        // per-wave fp32 transpose patch: 8 waves x 16x65 fp32 = 33.3KB into
        // the (dead) GEMM LDS region.
        float* Tt = reinterpret_cast<float*>(&L[0]);
        float* T = &Tt[wave * 16 * 65];
        float bvj[4];
        #pragma unroll
        for (int j = 0; j < 4; ++j) bvj[j] = bias[n0 + wn*64 + j*16 + qm];
        const int dcol = n0 + wn*64 + lane;            // read-phase column (d)
        #pragma unroll
        for (int i = 0; i < 4; ++i) {
            #pragma unroll
            for (int j = 0; j < 4; ++j)
                #pragma unroll
                for (int reg = 0; reg < 4; ++reg)
                    T[(qk*4 + reg) * 65 + j*16 + qm] = acc[i][j][reg] + bvj[j];
            __builtin_amdgcn_wave_barrier();
            float4 o[4];
            #pragma unroll
            for (int t4 = 0; t4 < 4; ++t4)
                o[t4] = make_float4(T[(t4*4 + 0) * 65 + lane], T[(t4*4 + 1) * 65 + lane],
                                    T[(t4*4 + 2) * 65 + lane], T[(t4*4 + 3) * 65 + lane]);
            const int r0 = m0 + wm*64 + i*16;
            const int bb = r0 >> 12, l0 = r0 & (SEQ - 1);
            float* dst = &out[((size_t)(bb * D_MODEL + dcol)) * SEQ + l0];
            #pragma unroll
            for (int t4 = 0; t4 < 4; ++t4)
                reinterpret_cast<float4*>(dst)[t4] = o[t4];
            __builtin_amdgcn_wave_barrier();
        }
    }
}

// ---------------------------------------------------------------------------
// scan2: MFMA chunked scan, fused in-LDS table build. 1024 blocks x 128 thr.
// (unchanged — verified)
// ---------------------------------------------------------------------------
__global__ __launch_bounds__(128) void scan2_kernel(
    float* __restrict__ ut, const float* __restrict__ A_log,
    const float* __restrict__ Bp, const float* __restrict__ Cp,
    const float* __restrict__ dtp, const float* __restrict__ Dpv)
{
    __shared__ __align__(16) u16 KT_s[64 * 64];
    __shared__ __align__(16) u16 RA_s[64 * 64];
    __shared__ __align__(16) u16 P2_s[64 * 64];
    __shared__ __align__(16) u16 SH[2][64 * 64];   // scratch during build; S/H after
    const int d = blockIdx.x, tid = threadIdx.x;
    const int w = tid >> 6, lane = tid & 63;
    const int qm = lane & 15, qk = lane >> 4;

    const float dt_d  = dtp[d];
    const float logdA = -expf(-A_log[d * D_STATE + lane]) * dt_d;
    const float r     = expf(logdA);
    const float dBn   = Bp[d * D_STATE + lane] * dt_d;
    const float Cv    = Cp[d * D_STATE + lane];
    const float rTn   = expf(logdA * 64.0f);
    const float Dpd   = Dpv[d];

    float* ug = ut + ((size_t)(w * D_MODEL + d)) * SEQ;

    // fp32 scratch inside SH (dead until S-phase): dB[64] | w[64] | k[64]
    float* dB_sh = reinterpret_cast<float*>(&SH[0][0]);
    float* w_sh  = dB_sh + 64;
    float* k_sh  = dB_sh + 128;

    // ---- U B-fragments (global fp32 -> hi/lo bf16), kk 0..1 = hi, 2..3 = lo
    bf16x8 Uf[4][4];
    #pragma unroll
    for (int ct = 0; ct < 4; ++ct) {
        const float* src = ug + (ct * 16 + qm) * 64;
        #pragma unroll
        for (int jb = 0; jb < 2; ++jb) {
            const float4 v0 = *reinterpret_cast<const float4*>(src + jb * 32 + qk * 8);
            const float4 v1 = *reinterpret_cast<const float4*>(src + jb * 32 + qk * 8 + 4);
            const float fv[8] = {v0.x, v0.y, v0.z, v0.w, v1.x, v1.y, v1.z, v1.w};
            BF8 hi, lo;
            #pragma unroll
            for (int i = 0; i < 8; ++i) {
                hi.e[i] = f2bf(fv[i]);
                lo.e[i] = f2bf(fv[i] - bf2f(hi.e[i]));
            }
            Uf[ct][jb]     = hi.v;
            Uf[ct][jb + 2] = lo.v;
        }
    }

    // ---- table build phase 1
    if (w == 0) {
        dB_sh[lane] = dBn;
        w_sh[lane]  = Cv * dBn;
        for (int o = 0; o < 8; ++o) {   // RA row n=lane: r^(63-j), j ascending
            float tmp[8];
            tmp[7] = expf(logdA * (float)(63 - (o * 8 + 7)));
            #pragma unroll
            for (int i = 6; i >= 0; --i) tmp[i] = tmp[i + 1] * r;
            u16 e[8];
            #pragma unroll
            for (int i = 0; i < 8; ++i) e[i] = f2bf(tmp[i]);
            *reinterpret_cast<uint4*>(&RA_s[lane * 64 + o * 8]) = pack8u(e);
        }
    } else {
        float p = Cv;                   // P2 column n=lane: C r^{t+1}
        for (int t = 0; t < 64; ++t) { p *= r; P2_s[t * 64 + lane] = f2bf(p); }
    }
    __syncthreads();
    // ---- table build phase 2 (wave0): k from P2, then KT rows
    if (w == 0) {
        float kacc = 0.f;
        if (lane == 0) {
            for (int n = 0; n < 64; ++n) kacc += w_sh[n];
        } else {
            const u16* prow = &P2_s[(lane - 1) * 64];
            for (int o = 0; o < 8; ++o) {
                BF8 p8; p8.q = *reinterpret_cast<const uint4*>(&prow[o * 8]);
                #pragma unroll
                for (int i = 0; i < 8; ++i) kacc += dB_sh[o * 8 + i] * bf2f(p8.e[i]);
            }
        }
        k_sh[lane] = kacc;              // same-wave LDS: in-order visibility
        for (int o = 0; o < 8; ++o) {   // KT row t=lane
            u16 e[8];
            #pragma unroll
            for (int i = 0; i < 8; ++i) {
                const int j = o * 8 + i;
                e[i] = (j <= lane) ? f2bf(k_sh[lane - j]) : (u16)0;
            }
            *reinterpret_cast<uint4*>(&KT_s[lane * 64 + o * 8]) = pack8u(e);
        }
    }
    __syncthreads();

    u16* sh = SH[w];
    {   // ---- S = RA_ext @ U_ext -> SH[w][c][n] bf16
        bf16x8 Af[4][2];
        #pragma unroll
        for (int nt = 0; nt < 4; ++nt)
            #pragma unroll
            for (int jb = 0; jb < 2; ++jb)
                Af[nt][jb] = *reinterpret_cast<const bf16x8*>(
                    &RA_s[(nt * 16 + qm) * 64 + jb * 32 + qk * 8]);
        f32x4 acc[4][4] = {};
        #pragma unroll
        for (int kk = 0; kk < 4; ++kk)
            #pragma unroll
            for (int nt = 0; nt < 4; ++nt)
                #pragma unroll
                for (int ct = 0; ct < 4; ++ct)
                    acc[nt][ct] = __builtin_amdgcn_mfma_f32_16x16x32_bf16(
                        Af[nt][kk & 1], Uf[ct][kk], acc[nt][ct], 0, 0, 0);
        #pragma unroll
        for (int nt = 0; nt < 4; ++nt)
            #pragma unroll
            for (int ct = 0; ct < 4; ++ct) {
                const int c = ct * 16 + qm, nn0 = nt * 16 + qk * 4;
                uint2 pk;
                pk.x = (u32)f2bf(acc[nt][ct][0]) | ((u32)f2bf(acc[nt][ct][1]) << 16);
                pk.y = (u32)f2bf(acc[nt][ct][2]) | ((u32)f2bf(acc[nt][ct][3]) << 16);
                *reinterpret_cast<uint2*>(&sh[c * 64 + nn0]) = pk;
            }
    }
    __syncthreads();

    {   // ---- serial inter-chunk hop, lane=n, batched: 16 reads ahead of chain
        float h = 0.f;
        u16* col = sh + lane;
        for (int b = 0; b < 4; ++b) {
            float sb[16];
            #pragma unroll
            for (int i = 0; i < 16; ++i) sb[i] = bf2f(col[(b * 16 + i) * 64]);
            #pragma unroll
            for (int i = 0; i < 16; ++i) {
                col[(b * 16 + i) * 64] = f2bf(h);
                h = rTn * h + dBn * sb[i];
            }
        }
    }
    __syncthreads();

    {   // ---- Y = KT_ext @ U_ext + P2 @ H ; epilogue adds Dp*u fp32, in-place
        bf16x8 Af[4][2];
        #pragma unroll
        for (int tt = 0; tt < 4; ++tt)
            #pragma unroll
            for (int jb = 0; jb < 2; ++jb)
                Af[tt][jb] = *reinterpret_cast<const bf16x8*>(
                    &KT_s[(tt * 16 + qm) * 64 + jb * 32 + qk * 8]);
        f32x4 acc[4][4] = {};
        #pragma unroll
        for (int kk = 0; kk < 4; ++kk)
            #pragma unroll
            for (int tt = 0; tt < 4; ++tt)
                #pragma unroll
                for (int ct = 0; ct < 4; ++ct)
                    acc[tt][ct] = __builtin_amdgcn_mfma_f32_16x16x32_bf16(
                        Af[tt][kk & 1], Uf[ct][kk], acc[tt][ct], 0, 0, 0);
        bf16x8 Pf[4][2];
        #pragma unroll
        for (int tt = 0; tt < 4; ++tt)
            #pragma unroll
            for (int kb = 0; kb < 2; ++kb)
                Pf[tt][kb] = *reinterpret_cast<const bf16x8*>(
                    &P2_s[(tt * 16 + qm) * 64 + kb * 32 + qk * 8]);
        #pragma unroll
        for (int ct = 0; ct < 4; ++ct)
            #pragma unroll
            for (int kb = 0; kb < 2; ++kb) {
                const bf16x8 Hf = *reinterpret_cast<const bf16x8*>(
                    &sh[(ct * 16 + qm) * 64 + kb * 32 + qk * 8]);
                #pragma unroll
                for (int tt = 0; tt < 4; ++tt)
                    acc[tt][ct] = __builtin_amdgcn_mfma_f32_16x16x32_bf16(
                        Pf[tt][kb], Hf, acc[tt][ct], 0, 0, 0);
            }
        #pragma unroll
        for (int tt = 0; tt < 4; ++tt)
            #pragma unroll
            for (int ct = 0; ct < 4; ++ct) {
                const int c = ct * 16 + qm, t0 = tt * 16 + qk * 4;
                float* dst = ug + c * 64 + t0;
                const float4 u4 = *reinterpret_cast<const float4*>(dst);
                float4 y;
                y.x = acc[tt][ct][0] + Dpd * u4.x;
                y.y = acc[tt][ct][1] + Dpd * u4.y;
                y.z = acc[tt][ct][2] + Dpd * u4.z;
                y.w = acc[tt][ct][3] + Dpd * u4.w;
                *reinterpret_cast<float4*>(dst) = y;
            }
    }
}

// ---------------------------------------------------------------------------
// transpose y_t[b][d][l] fp32 -> Ax rows [b*L][1024] bf16 for GEMM2.
// (unchanged — verified)
// ---------------------------------------------------------------------------
__global__ __launch_bounds__(256) void trans_kernel(
    const float* __restrict__ yt, u16* __restrict__ Ax)
{
    __shared__ float T[64 * 68];
    const int b = blockIdx.z, dx = blockIdx.y * 64, lx = blockIdx.x * 64;
    const int tid = threadIdx.x;
    const int t16 = tid >> 4, l16 = tid & 15;
    #pragma unroll
    for (int ii = 0; ii < 4; ++ii) {
        const int dd = ii * 16 + t16;
        const int ll = l16 * 4;
        float4 v = *reinterpret_cast<const float4*>(
            &yt[((size_t)(b * D_MODEL + dx + dd)) * SEQ + lx + ll]);
        *reinterpret_cast<float4*>(&T[dd * 68 + ll]) = v;
    }
    __syncthreads();
    #pragma unroll
    for (int ii = 0; ii < 4; ++ii) {
        const int ll = ii * 16 + t16;
        const int dd = l16 * 4;
        float v0 = T[(dd + 0) * 68 + ll], v1 = T[(dd + 1) * 68 + ll];
        float v2 = T[(dd + 2) * 68 + ll], v3 = T[(dd + 3) * 68 + ll];
        const size_t row = (size_t)b * SEQ + lx + ll;
        *reinterpret_cast<uint2*>(Ax + row * D_MODEL + dx + dd) =
            make_uint2((u32)f2bf(v0) | ((u32)f2bf(v1) << 16),
                       (u32)f2bf(v2) | ((u32)f2bf(v3) << 16));
    }
}

// ---------------------------------------------------------------------------
// Workspace (60 MB):
//   [0,  24MB)  Ax (16MB used)
//   [24, 56MB)  ut : [b][d][l] fp32 (scan in-place -> y_t)
//   [56, 58MB)  Bw1 : Win bf16
//   [58, 60MB)  Bw2 : Wout bf16
// ---------------------------------------------------------------------------
extern "C" void kernel_launch(void* const* d_in, const int* in_sizes, int n_in,
                              void* d_out, int out_size, void* d_ws, size_t ws_size,
                              hipStream_t stream) {
    const float* x     = (const float*)d_in[0];
    const float* Win   = (const float*)d_in[1];
    const float* bin   = (const float*)d_in[2];
    const float* A_log = (const float*)d_in[3];
    const float* Bp    = (const float*)d_in[4];
    const float* Cp    = (const float*)d_in[5];
    const float* Dpv   = (const float*)d_in[6];
    const float* dtp   = (const float*)d_in[7];
    const float* Wout  = (const float*)d_in[8];
    const float* bout  = (const float*)d_in[9];
    float* out = (float*)d_out;

    char* ws = (char*)d_ws;
    u16*   Ax  = (u16*)(ws);
    float* ut  = (float*)(ws + (size_t)25165824);
    u16*   Bw1 = (u16*)(ws + (size_t)58720256);
    u16*   Bw2 = (u16*)(ws + (size_t)60817408);

    prep_kernel<<<2560, 256, 0, stream>>>(x, Win, Wout, Ax, Bw1, Bw2);
    gemm_bt<1><<<256, 512, 0, stream>>>(Ax, Bw1, bin, ut);
    scan2_kernel<<<D_MODEL, 128, 0, stream>>>(ut, A_log, Bp, Cp, dtp, Dpv);
    trans_kernel<<<dim3(SEQ / 64, D_MODEL / 64, BATCH), 256, 0, stream>>>(ut, Ax);
    gemm_bt<0><<<256, 512, 0, stream>>>(Ax, Bw2, bout, out);
}

// Round 9
// 185.591 us; speedup vs baseline: 1.0300x; 1.0300x over previous
//
#include <hip/hip_runtime.h>
#include <cstdint>
#include <cstddef>

#define D_MODEL 1024
#define D_STATE 64
#define SEQ     4096
#define BATCH   2
#define MROWS   (BATCH*SEQ)   // 8192 rows of activations

typedef __bf16 bf16x8 __attribute__((ext_vector_type(8)));
typedef float  f32x4  __attribute__((ext_vector_type(4)));
typedef unsigned short u16;
typedef unsigned int   u32;

union BF8 { bf16x8 v; uint4 q; u16 e[8]; };

__device__ __forceinline__ u16 f2bf(float x) {
    u32 u = __float_as_uint(x);
    u32 r = u + 0x7FFFu + ((u >> 16) & 1u);   // RNE on bf16 boundary
    return (u16)(r >> 16);
}
__device__ __forceinline__ float bf2f(u16 h) {
    return __uint_as_float(((u32)h) << 16);
}
__device__ __forceinline__ uint4 pack8u(const u16* e) {
    return make_uint4((u32)e[0] | ((u32)e[1] << 16), (u32)e[2] | ((u32)e[3] << 16),
                      (u32)e[4] | ((u32)e[5] << 16), (u32)e[6] | ((u32)e[7] << 16));
}

// async global->LDS, 16B per lane. LDS dest is wave-uniform base + lane*16.
__device__ __forceinline__ void async16(const void* g, void* l) {
    __builtin_amdgcn_global_load_lds(
        (const __attribute__((address_space(1))) unsigned int*)(uintptr_t)g,
        (__attribute__((address_space(3))) unsigned int*)(uintptr_t)l,
        16, 0, 0);
}

// ---------------------------------------------------------------------------
// prep: flat fp32 -> bf16 convert over [ x | Win | Wout ] -> [ Ax | Bw1 | Bw2 ].
// (unchanged — verified)
// ---------------------------------------------------------------------------
__global__ __launch_bounds__(256) void prep_kernel(
    const float* __restrict__ x, const float* __restrict__ Win,
    const float* __restrict__ Wout,
    u16* __restrict__ Ax, u16* __restrict__ Bw1, u16* __restrict__ Bw2)
{
    const size_t base = (size_t)blockIdx.x * 4096 + threadIdx.x * 4;
    const float* src; u16* dst; size_t off;
    if (base < 8388608)        { src = x;    dst = Ax;  off = base; }
    else if (base < 9437184)   { src = Win;  dst = Bw1; off = base - 8388608; }
    else                       { src = Wout; dst = Bw2; off = base - 9437184; }
    #pragma unroll
    for (int i = 0; i < 4; ++i) {
        const float4 v = *reinterpret_cast<const float4*>(src + off + i * 1024);
        *reinterpret_cast<uint2*>(dst + off + i * 1024) =
            make_uint2((u32)f2bf(v.x) | ((u32)f2bf(v.y) << 16),
                       (u32)f2bf(v.z) | ((u32)f2bf(v.w) << 16));
    }
}

// ---------------------------------------------------------------------------
// gemm_bt: out[m,c] = sum_k A[m,k]*Bm[c,k] + bias[c], K=1024 bf16.
// REVERTED to the two-session-verified round-0 structure (128x128 tile,
// 4 waves, BK=64, double-buffered global_load_lds, XCD-grouped m-strips).
// The R0 T-stack variant measured neutral (+1.5%, within noise) -> keep the
// battle-tested kernel so this round's delta is attributable to the y-path.
// MODE 0: fp32 [m][1024] coalesced store. MODE 1: transposed store into
// ut[b][c][l] via per-wave LDS patch.
// ---------------------------------------------------------------------------
template<int MODE>
__global__ __launch_bounds__(256) void gemm_bt(
    const u16* __restrict__ A, const u16* __restrict__ Bm,
    const float* __restrict__ bias, float* __restrict__ out)
{
    __shared__ __align__(16) u16 As[2][128 * 64];
    __shared__ __align__(16) u16 Bs[2][128 * 64];
    const int bid  = blockIdx.x;
    const int slot = bid >> 3;
    const int m0 = ((bid & 7) * 8 + (slot >> 3)) * 128;   // XCD-grouped m-strips
    const int n0 = (slot & 7) * 128;
    const int tid = threadIdx.x;
    const int wave = tid >> 6, lane = tid & 63;
    const int wm = wave >> 1, wn = wave & 1;
    const int qm = lane & 15, qk = lane >> 4;
    f32x4 acc[4][4] = {};

    auto stage = [&](u16* Ad, u16* Bd, int k0) {
        #pragma unroll
        for (int it = 0; it < 4; ++it) {
            const int c   = it * 256 + tid;          // chunk 0..1023 (16B each)
            const int row = c >> 3, col = (c & 7) * 8;
            const int ldsbase = (it * 256 + wave * 64) * 8;   // wave-uniform
            async16(&A[(size_t)(m0 + row) * D_MODEL + k0 + col], Ad + ldsbase);
            async16(&Bm[(size_t)(n0 + row) * D_MODEL + k0 + col], Bd + ldsbase);
        }
    };
    auto compute = [&](const u16* As_, const u16* Bs_) {
        #pragma unroll
        for (int kk = 0; kk < 2; ++kk) {
            bf16x8 af[4], bg[4];
            #pragma unroll
            for (int i = 0; i < 4; ++i) {
                af[i] = *reinterpret_cast<const bf16x8*>(&As_[(wm*64 + i*16 + qm)*64 + kk*32 + qk*8]);
                bg[i] = *reinterpret_cast<const bf16x8*>(&Bs_[(wn*64 + i*16 + qm)*64 + kk*32 + qk*8]);
            }
            #pragma unroll
            for (int i = 0; i < 4; ++i)
                #pragma unroll
                for (int j = 0; j < 4; ++j)
                    acc[i][j] = __builtin_amdgcn_mfma_f32_16x16x32_bf16(af[i], bg[j], acc[i][j], 0, 0, 0);
        }
    };

    stage(As[0], Bs[0], 0);
    __syncthreads();
    #pragma unroll 1
    for (int kp = 0; kp < 7; ++kp) {
        stage(As[1], Bs[1], 128 * kp + 64);
        compute(As[0], Bs[0]);
        __syncthreads();
        stage(As[0], Bs[0], 128 * kp + 128);
        compute(As[1], Bs[1]);
        __syncthreads();
    }
    stage(As[1], Bs[1], 960);
    compute(As[0], Bs[0]);      // k=896
    __syncthreads();
    compute(As[1], Bs[1]);      // k=960

    // C/D layout: col = lane&15, row = (lane>>4)*4 + reg  [m89/m91-verified]
    if (MODE == 0) {
        #pragma unroll
        for (int i = 0; i < 4; ++i) {
            const int r0 = m0 + wm*64 + i*16 + qk*4;
            #pragma unroll
            for (int j = 0; j < 4; ++j) {
                const int c = n0 + wn*64 + j*16 + qm;
                const float bv = bias[c];
                #pragma unroll
                for (int reg = 0; reg < 4; ++reg)
                    out[(size_t)(r0 + reg) * D_MODEL + c] = acc[i][j][reg] + bv;
            }
        }
    } else {
        // As[0..] aliased as fp32 transpose patch (16.6KB; spills 256B into
        // As[1] which is dead after the final compute).
        float* Tt = reinterpret_cast<float*>(&As[0][0]);   // 4 waves x 16x65 fp32
        float* T = &Tt[wave * 16 * 65];
        float bvj[4];
        #pragma unroll
        for (int j = 0; j < 4; ++j) bvj[j] = bias[n0 + wn*64 + j*16 + qm];
        const int dcol = n0 + wn*64 + lane;            // read-phase column (d)
        #pragma unroll
        for (int i = 0; i < 4; ++i) {
            #pragma unroll
            for (int j = 0; j < 4; ++j)
                #pragma unroll
                for (int reg = 0; reg < 4; ++reg)
                    T[(qk*4 + reg) * 65 + j*16 + qm] = acc[i][j][reg] + bvj[j];
            __builtin_amdgcn_wave_barrier();
            float4 o[4];
            #pragma unroll
            for (int t4 = 0; t4 < 4; ++t4)
                o[t4] = make_float4(T[(t4*4 + 0) * 65 + lane], T[(t4*4 + 1) * 65 + lane],
                                    T[(t4*4 + 2) * 65 + lane], T[(t4*4 + 3) * 65 + lane]);
            const int r0 = m0 + wm*64 + i*16;
            const int bb = r0 >> 12, l0 = r0 & (SEQ - 1);
            float* dst = &out[((size_t)(bb * D_MODEL + dcol)) * SEQ + l0];
            #pragma unroll
            for (int t4 = 0; t4 < 4; ++t4)
                reinterpret_cast<float4*>(dst)[t4] = o[t4];
            __builtin_amdgcn_wave_barrier();
        }
    }
}

// ---------------------------------------------------------------------------
// scan2: MFMA chunked scan, fused in-LDS table build. 1024 blocks x 128 thr.
// CHANGED (y-bf16 path): epilogue folds the Dp*u skip into acc from the fp32
// row, then (after __syncthreads drains the u reads) writes y as bf16 into
// the FIRST HALF of the wave's own ut row (8KB of the 16KB fp32 row). Each
// (batch,d) row is touched only by its owning wave -> no cross-thread hazard
// beyond the in-block barrier. Halves scan2's HBM write (32->16 MB) and
// trans's read (32->16 MB). Bit-identical final output: trans previously
// applied f2bf to exactly these values.
// ---------------------------------------------------------------------------
__global__ __launch_bounds__(128) void scan2_kernel(
    float* __restrict__ ut, const float* __restrict__ A_log,
    const float* __restrict__ Bp, const float* __restrict__ Cp,
    const float* __restrict__ dtp, const float* __restrict__ Dpv)
{
    __shared__ __align__(16) u16 KT_s[64 * 64];
    __shared__ __align__(16) u16 RA_s[64 * 64];
    __shared__ __align__(16) u16 P2_s[64 * 64];
    __shared__ __align__(16) u16 SH[2][64 * 64];   // scratch during build; S/H after
    const int d = blockIdx.x, tid = threadIdx.x;
    const int w = tid >> 6, lane = tid & 63;
    const int qm = lane & 15, qk = lane >> 4;

    const float dt_d  = dtp[d];
    const float logdA = -expf(-A_log[d * D_STATE + lane]) * dt_d;
    const float r     = expf(logdA);
    const float dBn   = Bp[d * D_STATE + lane] * dt_d;
    const float Cv    = Cp[d * D_STATE + lane];
    const float rTn   = expf(logdA * 64.0f);
    const float Dpd   = Dpv[d];

    float* ug = ut + ((size_t)(w * D_MODEL + d)) * SEQ;

    // fp32 scratch inside SH (dead until S-phase): dB[64] | w[64] | k[64]
    float* dB_sh = reinterpret_cast<float*>(&SH[0][0]);
    float* w_sh  = dB_sh + 64;
    float* k_sh  = dB_sh + 128;

    // ---- U B-fragments (global fp32 -> hi/lo bf16), kk 0..1 = hi, 2..3 = lo
    bf16x8 Uf[4][4];
    #pragma unroll
    for (int ct = 0; ct < 4; ++ct) {
        const float* src = ug + (ct * 16 + qm) * 64;
        #pragma unroll
        for (int jb = 0; jb < 2; ++jb) {
            const float4 v0 = *reinterpret_cast<const float4*>(src + jb * 32 + qk * 8);
            const float4 v1 = *reinterpret_cast<const float4*>(src + jb * 32 + qk * 8 + 4);
            const float fv[8] = {v0.x, v0.y, v0.z, v0.w, v1.x, v1.y, v1.z, v1.w};
            BF8 hi, lo;
            #pragma unroll
            for (int i = 0; i < 8; ++i) {
                hi.e[i] = f2bf(fv[i]);
                lo.e[i] = f2bf(fv[i] - bf2f(hi.e[i]));
            }
            Uf[ct][jb]     = hi.v;
            Uf[ct][jb + 2] = lo.v;
        }
    }

    // ---- table build phase 1
    if (w == 0) {
        dB_sh[lane] = dBn;
        w_sh[lane]  = Cv * dBn;
        for (int o = 0; o < 8; ++o) {   // RA row n=lane: r^(63-j), j ascending
            float tmp[8];
            tmp[7] = expf(logdA * (float)(63 - (o * 8 + 7)));
            #pragma unroll
            for (int i = 6; i >= 0; --i) tmp[i] = tmp[i + 1] * r;
            u16 e[8];
            #pragma unroll
            for (int i = 0; i < 8; ++i) e[i] = f2bf(tmp[i]);
            *reinterpret_cast<uint4*>(&RA_s[lane * 64 + o * 8]) = pack8u(e);
        }
    } else {
        float p = Cv;                   // P2 column n=lane: C r^{t+1}
        for (int t = 0; t < 64; ++t) { p *= r; P2_s[t * 64 + lane] = f2bf(p); }
    }
    __syncthreads();
    // ---- table build phase 2 (wave0): k from P2, then KT rows
    if (w == 0) {
        float kacc = 0.f;
        if (lane == 0) {
            for (int n = 0; n < 64; ++n) kacc += w_sh[n];
        } else {
            const u16* prow = &P2_s[(lane - 1) * 64];
            for (int o = 0; o < 8; ++o) {
                BF8 p8; p8.q = *reinterpret_cast<const uint4*>(&prow[o * 8]);
                #pragma unroll
                for (int i = 0; i < 8; ++i) kacc += dB_sh[o * 8 + i] * bf2f(p8.e[i]);
            }
        }
        k_sh[lane] = kacc;              // same-wave LDS: in-order visibility
        for (int o = 0; o < 8; ++o) {   // KT row t=lane
            u16 e[8];
            #pragma unroll
            for (int i = 0; i < 8; ++i) {
                const int j = o * 8 + i;
                e[i] = (j <= lane) ? f2bf(k_sh[lane - j]) : (u16)0;
            }
            *reinterpret_cast<uint4*>(&KT_s[lane * 64 + o * 8]) = pack8u(e);
        }
    }
    __syncthreads();

    u16* sh = SH[w];
    {   // ---- S = RA_ext @ U_ext -> SH[w][c][n] bf16
        bf16x8 Af[4][2];
        #pragma unroll
        for (int nt = 0; nt < 4; ++nt)
            #pragma unroll
            for (int jb = 0; jb < 2; ++jb)
                Af[nt][jb] = *reinterpret_cast<const bf16x8*>(
                    &RA_s[(nt * 16 + qm) * 64 + jb * 32 + qk * 8]);
        f32x4 acc[4][4] = {};
        #pragma unroll
        for (int kk = 0; kk < 4; ++kk)
            #pragma unroll
            for (int nt = 0; nt < 4; ++nt)
                #pragma unroll
                for (int ct = 0; ct < 4; ++ct)
                    acc[nt][ct] = __builtin_amdgcn_mfma_f32_16x16x32_bf16(
                        Af[nt][kk & 1], Uf[ct][kk], acc[nt][ct], 0, 0, 0);
        #pragma unroll
        for (int nt = 0; nt < 4; ++nt)
            #pragma unroll
            for (int ct = 0; ct < 4; ++ct) {
                const int c = ct * 16 + qm, nn0 = nt * 16 + qk * 4;
                uint2 pk;
                pk.x = (u32)f2bf(acc[nt][ct][0]) | ((u32)f2bf(acc[nt][ct][1]) << 16);
                pk.y = (u32)f2bf(acc[nt][ct][2]) | ((u32)f2bf(acc[nt][ct][3]) << 16);
                *reinterpret_cast<uint2*>(&sh[c * 64 + nn0]) = pk;
            }
    }
    __syncthreads();

    {   // ---- serial inter-chunk hop, lane=n, batched: 16 reads ahead of chain
        float h = 0.f;
        u16* col = sh + lane;
        for (int b = 0; b < 4; ++b) {
            float sb[16];
            #pragma unroll
            for (int i = 0; i < 16; ++i) sb[i] = bf2f(col[(b * 16 + i) * 64]);
            #pragma unroll
            for (int i = 0; i < 16; ++i) {
                col[(b * 16 + i) * 64] = f2bf(h);
                h = rTn * h + dBn * sb[i];
            }
        }
    }
    __syncthreads();

    {   // ---- Y = KT_ext @ U_ext + P2 @ H ; fold Dp*u skip; write y bf16
        bf16x8 Af[4][2];
        #pragma unroll
        for (int tt = 0; tt < 4; ++tt)
            #pragma unroll
            for (int jb = 0; jb < 2; ++jb)
                Af[tt][jb] = *reinterpret_cast<const bf16x8*>(
                    &KT_s[(tt * 16 + qm) * 64 + jb * 32 + qk * 8]);
        f32x4 acc[4][4] = {};
        #pragma unroll
        for (int kk = 0; kk < 4; ++kk)
            #pragma unroll
            for (int tt = 0; tt < 4; ++tt)
                #pragma unroll
                for (int ct = 0; ct < 4; ++ct)
                    acc[tt][ct] = __builtin_amdgcn_mfma_f32_16x16x32_bf16(
                        Af[tt][kk & 1], Uf[ct][kk], acc[tt][ct], 0, 0, 0);
        bf16x8 Pf[4][2];
        #pragma unroll
        for (int tt = 0; tt < 4; ++tt)
            #pragma unroll
            for (int kb = 0; kb < 2; ++kb)
                Pf[tt][kb] = *reinterpret_cast<const bf16x8*>(
                    &P2_s[(tt * 16 + qm) * 64 + kb * 32 + qk * 8]);
        #pragma unroll
        for (int ct = 0; ct < 4; ++ct)
            #pragma unroll
            for (int kb = 0; kb < 2; ++kb) {
                const bf16x8 Hf = *reinterpret_cast<const bf16x8*>(
                    &sh[(ct * 16 + qm) * 64 + kb * 32 + qk * 8]);
                #pragma unroll
                for (int tt = 0; tt < 4; ++tt)
                    acc[tt][ct] = __builtin_amdgcn_mfma_f32_16x16x32_bf16(
                        Pf[tt][kb], Hf, acc[tt][ct], 0, 0, 0);
            }
        // fold skip: read ALL u fp32 first (no overwrite yet)
        #pragma unroll
        for (int tt = 0; tt < 4; ++tt)
            #pragma unroll
            for (int ct = 0; ct < 4; ++ct) {
                const int c = ct * 16 + qm, t0 = tt * 16 + qk * 4;
                const float4 u4 = *reinterpret_cast<const float4*>(ug + c * 64 + t0);
                acc[tt][ct][0] += Dpd * u4.x;
                acc[tt][ct][1] += Dpd * u4.y;
                acc[tt][ct][2] += Dpd * u4.z;
                acc[tt][ct][3] += Dpd * u4.w;
            }
        __syncthreads();   // drain u reads before the bf16 overwrite of row halves
        u16* yb = reinterpret_cast<u16*>(ug);   // first 8KB of own 16KB row
        #pragma unroll
        for (int tt = 0; tt < 4; ++tt)
            #pragma unroll
            for (int ct = 0; ct < 4; ++ct) {
                const int c = ct * 16 + qm, t0 = tt * 16 + qk * 4;
                uint2 pk;
                pk.x = (u32)f2bf(acc[tt][ct][0]) | ((u32)f2bf(acc[tt][ct][1]) << 16);
                pk.y = (u32)f2bf(acc[tt][ct][2]) | ((u32)f2bf(acc[tt][ct][3]) << 16);
                *reinterpret_cast<uint2*>(&yb[c * 64 + t0]) = pk;
            }
    }
}

// ---------------------------------------------------------------------------
// transpose y bf16 [b][d][l] (packed in first half of ut rows, row stride
// 8192 u16) -> Ax rows [b*L][1024] bf16 for GEMM2.
// CHANGED: load phase reads uint2 (4 bf16) + bf2f-expands into the SAME
// verified fp32 LDS transpose; read/store phase identical (f2bf at the same
// values -> bit-identical Ax).
// ---------------------------------------------------------------------------
__global__ __launch_bounds__(256) void trans_kernel(
    const float* __restrict__ yt, u16* __restrict__ Ax)
{
    __shared__ float T[64 * 68];
    const int b = blockIdx.z, dx = blockIdx.y * 64, lx = blockIdx.x * 64;
    const int tid = threadIdx.x;
    const int t16 = tid >> 4, l16 = tid & 15;
    const u16* yb = reinterpret_cast<const u16*>(yt);
    #pragma unroll
    for (int ii = 0; ii < 4; ++ii) {
        const int dd = ii * 16 + t16;
        const int ll = l16 * 4;
        const uint2 v = *reinterpret_cast<const uint2*>(
            &yb[((size_t)(b * D_MODEL + dx + dd)) * (SEQ * 2) + lx + ll]);
        *reinterpret_cast<float4*>(&T[dd * 68 + ll]) =
            make_float4(bf2f((u16)(v.x & 0xFFFFu)), bf2f((u16)(v.x >> 16)),
                        bf2f((u16)(v.y & 0xFFFFu)), bf2f((u16)(v.y >> 16)));
    }
    __syncthreads();
    #pragma unroll
    for (int ii = 0; ii < 4; ++ii) {
        const int ll = ii * 16 + t16;
        const int dd = l16 * 4;
        float v0 = T[(dd + 0) * 68 + ll], v1 = T[(dd + 1) * 68 + ll];
        float v2 = T[(dd + 2) * 68 + ll], v3 = T[(dd + 3) * 68 + ll];
        const size_t row = (size_t)b * SEQ + lx + ll;
        *reinterpret_cast<uint2*>(Ax + row * D_MODEL + dx + dd) =
            make_uint2((u32)f2bf(v0) | ((u32)f2bf(v1) << 16),
                       (u32)f2bf(v2) | ((u32)f2bf(v3) << 16));
    }
}

// ---------------------------------------------------------------------------
// Workspace (60 MB):
//   [0,  24MB)  Ax (16MB used)
//   [24, 56MB)  ut : [b][d][l] fp32 (scan writes y bf16 into row first-halves)
//   [56, 58MB)  Bw1 : Win bf16
//   [58, 60MB)  Bw2 : Wout bf16
// ---------------------------------------------------------------------------
extern "C" void kernel_launch(void* const* d_in, const int* in_sizes, int n_in,
                              void* d_out, int out_size, void* d_ws, size_t ws_size,
                              hipStream_t stream) {
    const float* x     = (const float*)d_in[0];
    const float* Win   = (const float*)d_in[1];
    const float* bin   = (const float*)d_in[2];
    const float* A_log = (const float*)d_in[3];
    const float* Bp    = (const float*)d_in[4];
    const float* Cp    = (const float*)d_in[5];
    const float* Dpv   = (const float*)d_in[6];
    const float* dtp   = (const float*)d_in[7];
    const float* Wout  = (const float*)d_in[8];
    const float* bout  = (const float*)d_in[9];
    float* out = (float*)d_out;

    char* ws = (char*)d_ws;
    u16*   Ax  = (u16*)(ws);
    float* ut  = (float*)(ws + (size_t)25165824);
    u16*   Bw1 = (u16*)(ws + (size_t)58720256);
    u16*   Bw2 = (u16*)(ws + (size_t)60817408);

    prep_kernel<<<2560, 256, 0, stream>>>(x, Win, Wout, Ax, Bw1, Bw2);
    gemm_bt<1><<<512, 256, 0, stream>>>(Ax, Bw1, bin, ut);
    scan2_kernel<<<D_MODEL, 128, 0, stream>>>(ut, A_log, Bp, Cp, dtp, Dpv);
    trans_kernel<<<dim3(SEQ / 64, D_MODEL / 64, BATCH), 256, 0, stream>>>(ut, Ax);
    gemm_bt<0><<<512, 256, 0, stream>>>(Ax, Bw2, bout, out);
}